// Round 2
// 404.632 us; speedup vs baseline: 1.3544x; 1.3544x over previous
//
#include <hip/hip_runtime.h>

#define N   128
#define NC  40
#define BB  4096

typedef unsigned short u16;
typedef unsigned int   u32;
typedef float f32x4 __attribute__((ext_vector_type(4)));
typedef int   i32x4 __attribute__((ext_vector_type(4)));
typedef int   i32x2 __attribute__((ext_vector_type(2)));

#define AS1 __attribute__((address_space(1)))
#define AS3 __attribute__((address_space(3)))

// Inline-asm MFMA. s_nop 1 guards the VALU-write -> MFMA-srcA/B/C read hazard
// (compiler can't see inside the asm to insert wait states).
#define MFMA16(acc, a, b) \
  asm("s_nop 1\n\tv_mfma_f32_16x16x32_bf16 %0, %1, %2, %0" \
      : "+v"(acc) : "v"(a), "v"(b))
// MFMA-write -> VALU-read hazard fence (20 cycles), tied to the acc register
// so the scheduler cannot hoist reads above it.
#define ACCFENCE(a) asm("s_nop 7\n\ts_nop 7\n\ts_nop 3" : "+v"(a))

__device__ __forceinline__ u16 rne16(float f) {
  u32 u = __float_as_uint(f);
  return (u16)((u + 0x7fffu + ((u >> 16) & 1u)) >> 16);
}

// Split f0,f1 into packed bf16 hi-word and lo-word (hi = truncate, lo = RNE of
// residual; combined capture error <= ~2^-17 relative).
__device__ __forceinline__ void cvt2(float f0, float f1, u32& hw, u32& lw) {
  u32 u0 = __float_as_uint(f0), u1 = __float_as_uint(f1);
  hw = (u0 >> 16) | (u1 & 0xffff0000u);
  float r0 = f0 - __uint_as_float(u0 & 0xffff0000u);
  float r1 = f1 - __uint_as_float(u1 & 0xffff0000u);
  u32 v0 = __float_as_uint(r0), v1 = __float_as_uint(r1);
  lw = ((v0 + 0x7fffu + ((v0 >> 16) & 1u)) >> 16) |
       ((v1 + 0x7fffu + ((v1 >> 16) & 1u)) & 0xffff0000u);
}

__device__ __forceinline__ void cvt_frag(f32x4 x0, f32x4 x1, i32x4& hi, i32x4& lo) {
  u32 h0, h1, h2, h3, l0, l1, l2, l3;
  cvt2(x0.x, x0.y, h0, l0);
  cvt2(x0.z, x0.w, h1, l1);
  cvt2(x1.x, x1.y, h2, l2);
  cvt2(x1.z, x1.w, h3, l3);
  i32x4 h = {(int)h0, (int)h1, (int)h2, (int)h3};
  i32x4 l = {(int)l0, (int)l1, (int)l2, (int)l3};
  hi = h; lo = l;
}

// ---------------------------------------------------------------------------
// prep1: A_norm = D^-1/2 (A + I) D^-1/2 from tril edge weights. 1 block.
// ---------------------------------------------------------------------------
__global__ void prep_anorm(const float* __restrict__ edge_w,
                           float* __restrict__ An_out) {
    __shared__ float Ah[N][N + 1];
    __shared__ float dinv[N];
    const int t  = threadIdx.x;
    const int i  = t >> 1;
    const int jh = (t & 1) * 64;
    for (int jj = 0; jj < 64; ++jj) {
        int j  = jh + jj;
        int hi = i >= j ? i : j;
        int lo = i >= j ? j : i;
        float a = edge_w[hi * (hi + 1) / 2 + lo];
        if (i == j) a += 1.0f;
        Ah[i][j] = a;
    }
    __syncthreads();
    if (t < N) {
        float s = 0.0f;
        for (int j = 0; j < N; ++j) s += Ah[t][j];
        dinv[t] = s > 0.0f ? 1.0f / sqrtf(s) : 0.0f;
    }
    __syncthreads();
    for (int jj = 0; jj < 64; ++jj) {
        int j = jh + jj;
        An_out[i * N + j] = dinv[i] * Ah[i][j] * dinv[j];
    }
}

// ---------------------------------------------------------------------------
// prep2: A2 = An @ An. 128 blocks x 128 threads.
// ---------------------------------------------------------------------------
__global__ void prep_a2(const float* __restrict__ An, float* __restrict__ A2) {
    const int i = blockIdx.x;
    const int j = threadIdx.x;
    float acc = 0.0f;
    for (int k = 0; k < N; ++k)
        acc += An[i * N + k] * An[k * N + j];
    A2[i * N + j] = acc;
}

// ---------------------------------------------------------------------------
// prep3: split lin_w and A2 into bf16 hi/lo, pre-arranged in MFMA fragment
// order so the main kernel loads them as coalesced dwordx4 per lane.
// Fragment k-pattern for 16x16x32: k = 32*kt + 4*(lane>>4) + (j&3) + 16*(j>>2).
// W (B-operand, 128x64): frag fr = kt*4+nt (16 frags), idx (fr*64+lane)*8+j.
// A2 (A-operand, 128x128): frag fr = kt*8+mt (32 frags), idx (fr*64+lane)*8+j.
// ---------------------------------------------------------------------------
__global__ void prep_frag(const float* __restrict__ A2,
                          const float* __restrict__ lin_w,
                          u16* __restrict__ wfh, u16* __restrict__ wfl,
                          u16* __restrict__ afh, u16* __restrict__ afl) {
  int g = blockIdx.x * 256 + threadIdx.x;   // 0..3071
  if (g < 1024) {
    int fr = g >> 6, l = g & 63;
    int kt = fr >> 2, nt = fr & 3;
    int q = l >> 4, cc = l & 15;
#pragma unroll
    for (int j = 0; j < 8; ++j) {
      int k = 32 * kt + 4 * q + (j & 3) + 16 * (j >> 2);
      float v = lin_w[k * 64 + 16 * nt + cc];
      u32 u = __float_as_uint(v);
      wfh[(fr * 64 + l) * 8 + j] = (u16)(u >> 16);
      wfl[(fr * 64 + l) * 8 + j] = rne16(v - __uint_as_float(u & 0xffff0000u));
    }
  } else if (g < 3072) {
    int g2 = g - 1024;
    int fr = g2 >> 6, l = g2 & 63;        // fr = kt*8 + mt
    int kt = fr >> 3, mt = fr & 7;
    int q = l >> 4, rr = l & 15;
#pragma unroll
    for (int j = 0; j < 8; ++j) {
      int k = 32 * kt + 4 * q + (j & 3) + 16 * (j >> 2);
      float v = A2[(16 * mt + rr) * N + k];
      u32 u = __float_as_uint(v);
      afh[(fr * 64 + l) * 8 + j] = (u16)(u >> 16);
      afl[(fr * 64 + l) * 8 + j] = rne16(v - __uint_as_float(u & 0xffff0000u));
    }
  }
}

// ---------------------------------------------------------------------------
// Stage one 32-column chunk of x[b] (128 rows x 32 f, fp32, 16 KB) into LDS
// via global_load_lds width=16. LDS dest is linear (base + lane*16): cell
// layout [row][slot] with content col 4*(slot ^ (row&7)) achieved by
// PRE-SWIZZLING the per-lane GLOBAL source address (m173 pattern) ->
// bank-uniform b128 fragment reads. c in 0..3 ONLY (4 chunks of 32 cols).
// ---------------------------------------------------------------------------
__device__ __forceinline__ void stage_chunk(const float* xb, int c,
                                            float* dstbase, int t) {
#pragma unroll
  for (int i = 0; i < 4; ++i) {
    int g = t + 256 * i;           // 16B cell index, 1024 cells total
    int row = g >> 3, s = g & 7;
    const float* src = xb + row * N + c * 32 + 4 * (s ^ (row & 7));
    float* ldsb = dstbase + 256 * (t >> 6) + 1024 * i;   // wave-uniform base
    __builtin_amdgcn_global_load_lds((AS1 void*)src, (AS3 void*)ldsb, 16, 0, 0);
  }
}

// ---------------------------------------------------------------------------
// Main fused kernel, one batch element per block, 4 waves.
// Wave w owns output rows 32w..32w+31 (m-tiles 2w, 2w+1) in both phases.
//   Phase 1: Y = X @ W   (X streamed HBM->LDS in 4 k-chunks, W frags from L2)
//   Phase 2: H = A2 @ Y  (A2 frags from L2, Y^T hi/lo bf16 in LDS)
// Split-bf16 (hi+lo, 3 products; lo*lo dropped ~2^-18) on the matrix pipe.
// LDS: 2x16KB x-dbuf + 2x16.5KB yt = 65 KB -> 2 blocks/CU.
// ---------------------------------------------------------------------------
__global__ __launch_bounds__(256, 2) void dgcnn_main(
    const float* __restrict__ x,
    const u16* __restrict__ wfh_, const u16* __restrict__ wfl_,
    const u16* __restrict__ afh_, const u16* __restrict__ afl_,
    const float* __restrict__ lin_b, const float* __restrict__ conv_w,
    const float* __restrict__ conv_b, const float* __restrict__ fc_w,
    const float* __restrict__ fc_b, float* __restrict__ out) {
  __shared__ __align__(16) float xs[2][4096];      // 32 KB x chunk dbuf
  __shared__ __align__(16) u16 ythi[64 * 132];     // Y^T hi, stride 132
  __shared__ __align__(16) u16 ytlo[64 * 132];     // Y^T lo

  const int t    = threadIdx.x;
  const int b    = blockIdx.x;
  const int w    = t >> 6;
  const int lane = t & 63;
  const int q    = lane >> 4;
  const int cl   = lane & 15;

  const float* xb = x + (size_t)b * (N * N);
  const i32x4* wfh4 = (const i32x4*)wfh_;
  const i32x4* wfl4 = (const i32x4*)wfl_;
  const i32x4* afh4 = (const i32x4*)afh_;
  const i32x4* afl4 = (const i32x4*)afl_;

  const f32x4 fzero = {0.f, 0.f, 0.f, 0.f};
  f32x4 acc[2][4];
#pragma unroll
  for (int m = 0; m < 2; ++m)
#pragma unroll
    for (int n = 0; n < 4; ++n) acc[m][n] = fzero;

  stage_chunk(xb, 0, &xs[0][0], t);
  __syncthreads();   // compiler emits vmcnt(0) before s_barrier -> chunk ready

  // ---------------- Phase 1: Y = X @ W, 4 k-chunks, double-buffered --------
#pragma unroll 1
  for (int c = 0; c < 4; ++c) {
    if (c < 3) stage_chunk(xb, c + 1, &xs[(c + 1) & 1][0], t);

    // W B-frags (hi/lo) straight from L2, coalesced 16B/lane. fr = c*4+nt < 16.
    i32x4 bh[4], bl[4];
#pragma unroll
    for (int nt = 0; nt < 4; ++nt) {
      bh[nt] = wfh4[(c * 4 + nt) * 64 + lane];
      bl[nt] = wfl4[(c * 4 + nt) * 64 + lane];
    }
    // X A-frags: swizzled b128 reads + in-register hi/lo split
    const float* bufp = &xs[c & 1][0];
    i32x4 ah[2], al[2];
#pragma unroll
    for (int m = 0; m < 2; ++m) {
      int row = 32 * w + 16 * m + cl;
      const float* rp = bufp + row * 32;
      int rx = row & 7;
      f32x4 x0 = *(const f32x4*)(rp + 4 * (q ^ rx));        // k 4q..4q+3
      f32x4 x1 = *(const f32x4*)(rp + 4 * ((q + 4) ^ rx));  // k 16+4q..
      cvt_frag(x0, x1, ah[m], al[m]);
    }
#pragma unroll
    for (int m = 0; m < 2; ++m)
#pragma unroll
      for (int nt = 0; nt < 4; ++nt) {
        MFMA16(acc[m][nt], ah[m], bh[nt]);
        MFMA16(acc[m][nt], ah[m], bl[nt]);
        MFMA16(acc[m][nt], al[m], bh[nt]);
      }
    __syncthreads();
  }

#pragma unroll
  for (int m = 0; m < 2; ++m)
#pragma unroll
    for (int nt = 0; nt < 4; ++nt) ACCFENCE(acc[m][nt]);

  // Y -> Y^T hi/lo bf16 in LDS. D layout: row = 16*mt + 4q + r, col = 16nt+cl.
#pragma unroll
  for (int m = 0; m < 2; ++m) {
    int j0 = 32 * w + 16 * m + 4 * q;
#pragma unroll
    for (int nt = 0; nt < 4; ++nt) {
      int rbase = (16 * nt + cl) * 132 + j0;
      f32x4 v = acc[m][nt];
      u32 hw0, lw0, hw1, lw1;
      cvt2(v.x, v.y, hw0, lw0);
      cvt2(v.z, v.w, hw1, lw1);
      i32x2 sh = {(int)hw0, (int)hw1};
      i32x2 sl = {(int)lw0, (int)lw1};
      *(i32x2*)&ythi[rbase] = sh;
      *(i32x2*)&ytlo[rbase] = sl;
      acc[m][nt] = fzero;
    }
  }
  __syncthreads();

  // ---------------- Phase 2: H = A2 @ Y (barrier-free; Y resident) ---------
#pragma unroll 2
  for (int kt = 0; kt < 4; ++kt) {
    i32x4 a2h[2], a2l[2];
#pragma unroll
    for (int m = 0; m < 2; ++m) {
      int fr = kt * 8 + 2 * w + m;
      a2h[m] = afh4[fr * 64 + lane];
      a2l[m] = afl4[fr * 64 + lane];
    }
#pragma unroll
    for (int nt = 0; nt < 4; ++nt) {
      int rbase = (16 * nt + cl) * 132 + 32 * kt + 4 * q;
      i32x2 p0 = *(const i32x2*)&ythi[rbase];
      i32x2 p1 = *(const i32x2*)&ythi[rbase + 16];
      i32x2 r0 = *(const i32x2*)&ytlo[rbase];
      i32x2 r1 = *(const i32x2*)&ytlo[rbase + 16];
      i32x4 yh = {p0.x, p0.y, p1.x, p1.y};
      i32x4 yl = {r0.x, r0.y, r1.x, r1.y};
#pragma unroll
      for (int m = 0; m < 2; ++m) {
        MFMA16(acc[m][nt], a2h[m], yh);
        MFMA16(acc[m][nt], a2h[m], yl);
        MFMA16(acc[m][nt], a2l[m], yh);
      }
    }
  }

#pragma unroll
  for (int m = 0; m < 2; ++m)
#pragma unroll
    for (int nt = 0; nt < 4; ++nt) ACCFENCE(acc[m][nt]);

  // Epilogue: relu(H + lin_b) * conv_w, partial pool into LDS (xs reused).
  float* ps   = &xs[0][0];      // 16 x 64 partials
  float* pool = &xs[0][1024];   // 64 pooled
  float hb[4];
#pragma unroll
  for (int nt = 0; nt < 4; ++nt) hb[nt] = lin_b[16 * nt + cl];
  f32x4 cw0 = *(const f32x4*)(conv_w + 32 * w + 4 * q);
  f32x4 cw1 = *(const f32x4*)(conv_w + 32 * w + 16 + 4 * q);
#pragma unroll
  for (int nt = 0; nt < 4; ++nt) {
    f32x4 v0 = acc[0][nt], v1 = acc[1][nt];
    float s = 0.f;
    s += fmaxf(v0.x + hb[nt], 0.f) * cw0.x;
    s += fmaxf(v0.y + hb[nt], 0.f) * cw0.y;
    s += fmaxf(v0.z + hb[nt], 0.f) * cw0.z;
    s += fmaxf(v0.w + hb[nt], 0.f) * cw0.w;
    s += fmaxf(v1.x + hb[nt], 0.f) * cw1.x;
    s += fmaxf(v1.y + hb[nt], 0.f) * cw1.y;
    s += fmaxf(v1.z + hb[nt], 0.f) * cw1.z;
    s += fmaxf(v1.w + hb[nt], 0.f) * cw1.w;
    ps[(w * 4 + q) * 64 + 16 * nt + cl] = s;
  }
  __syncthreads();
  if (t < 64) {
    float s = conv_b[0];
#pragma unroll
    for (int i = 0; i < 16; ++i) s += ps[i * 64 + t];
    pool[t] = fmaxf(s, 0.f);
  }
  __syncthreads();
  if (t < NC) {
    float o = fc_b[t];
#pragma unroll
    for (int h = 0; h < 64; ++h) o += pool[h] * fc_w[h * NC + t];
    out[(size_t)b * NC + t] = o;
  }
}

// ---------------------------------------------------------------------------
extern "C" void kernel_launch(void* const* d_in, const int* in_sizes, int n_in,
                              void* d_out, int out_size, void* d_ws, size_t ws_size,
                              hipStream_t stream) {
    const float* x      = (const float*)d_in[0];
    const float* edge_w = (const float*)d_in[1];
    const float* lin_w  = (const float*)d_in[2];
    const float* lin_b  = (const float*)d_in[3];
    const float* conv_w = (const float*)d_in[4];
    const float* conv_b = (const float*)d_in[5];
    const float* fc_w   = (const float*)d_in[6];
    const float* fc_b   = (const float*)d_in[7];
    float* out = (float*)d_out;

    // workspace layout: A2(64K) An(64K) wfh(16K) wfl(16K) afh(32K) afl(32K)
    float* A2 = (float*)d_ws;
    float* An = A2 + N * N;
    u16* wfh = (u16*)(An + N * N);
    u16* wfl = wfh + 8192;
    u16* afh = wfl + 8192;
    u16* afl = afh + 16384;

    prep_anorm<<<1, 256, 0, stream>>>(edge_w, An);
    prep_a2<<<N, N, 0, stream>>>(An, A2);
    prep_frag<<<12, 256, 0, stream>>>(A2, lin_w, wfh, wfl, afh, afl);
    dgcnn_main<<<BB, 256, 0, stream>>>(x, wfh, wfl, afh, afl, lin_b, conv_w,
                                       conv_b, fc_w, fc_b, out);
}

// Round 3
// 394.827 us; speedup vs baseline: 1.3880x; 1.0248x over previous
//
#include <hip/hip_runtime.h>

#define N   128
#define NC  40
#define BB  4096
#define YS  140   // Y^T row stride in u16: byte-stride 280 ≡ 6 banks (mod 32);
                  // 6*cl bijective on even residues -> b64 reads/writes hit the
                  // 512B/wave LDS bandwidth floor (4 accesses/bank), vs 132
                  // which used only even banks (2x worse).

typedef unsigned short u16;
typedef unsigned int   u32;
typedef float f32x4 __attribute__((ext_vector_type(4)));
typedef int   i32x2 __attribute__((ext_vector_type(2)));
typedef short bf16x8 __attribute__((ext_vector_type(8)));  // 4 VGPR MFMA frag

__device__ __forceinline__ u16 rne16(float f) {
  u32 u = __float_as_uint(f);
  return (u16)((u + 0x7fffu + ((u >> 16) & 1u)) >> 16);
}

// Split f0,f1 into packed bf16 hi-word (truncate) and lo-word (RNE of
// residual); combined capture error <= ~2^-17 relative.
__device__ __forceinline__ void cvt2(float f0, float f1, u32& hw, u32& lw) {
  u32 u0 = __float_as_uint(f0), u1 = __float_as_uint(f1);
  hw = (u0 >> 16) | (u1 & 0xffff0000u);
  float r0 = f0 - __uint_as_float(u0 & 0xffff0000u);
  float r1 = f1 - __uint_as_float(u1 & 0xffff0000u);
  u32 v0 = __float_as_uint(r0), v1 = __float_as_uint(r1);
  lw = ((v0 + 0x7fffu + ((v0 >> 16) & 1u)) >> 16) |
       ((v1 + 0x7fffu + ((v1 >> 16) & 1u)) & 0xffff0000u);
}

__device__ __forceinline__ bf16x8 pack8(u32 a, u32 b, u32 c, u32 d) {
  union { u32 w[4]; bf16x8 v; } u;
  u.w[0] = a; u.w[1] = b; u.w[2] = c; u.w[3] = d;
  return u.v;
}

__device__ __forceinline__ void cvt_frag(f32x4 x0, f32x4 x1,
                                         bf16x8& hi, bf16x8& lo) {
  u32 h0, h1, h2, h3, l0, l1, l2, l3;
  cvt2(x0.x, x0.y, h0, l0);
  cvt2(x0.z, x0.w, h1, l1);
  cvt2(x1.x, x1.y, h2, l2);
  cvt2(x1.z, x1.w, h3, l3);
  hi = pack8(h0, h1, h2, h3);
  lo = pack8(l0, l1, l2, l3);
}

#define MFMA(a, b, c) __builtin_amdgcn_mfma_f32_16x16x32_bf16(a, b, c, 0, 0, 0)

// ---------------------------------------------------------------------------
// prep1: A_norm = D^-1/2 (A + I) D^-1/2 from tril edge weights. 1 block.
// ---------------------------------------------------------------------------
__global__ void prep_anorm(const float* __restrict__ edge_w,
                           float* __restrict__ An_out) {
    __shared__ float Ah[N][N + 1];
    __shared__ float dinv[N];
    const int t  = threadIdx.x;
    const int i  = t >> 1;
    const int jh = (t & 1) * 64;
    for (int jj = 0; jj < 64; ++jj) {
        int j  = jh + jj;
        int hi = i >= j ? i : j;
        int lo = i >= j ? j : i;
        float a = edge_w[hi * (hi + 1) / 2 + lo];
        if (i == j) a += 1.0f;
        Ah[i][j] = a;
    }
    __syncthreads();
    if (t < N) {
        float s = 0.0f;
        for (int j = 0; j < N; ++j) s += Ah[t][j];
        dinv[t] = s > 0.0f ? 1.0f / sqrtf(s) : 0.0f;
    }
    __syncthreads();
    for (int jj = 0; jj < 64; ++jj) {
        int j = jh + jj;
        An_out[i * N + j] = dinv[i] * Ah[i][j] * dinv[j];
    }
}

// ---------------------------------------------------------------------------
// prep2: A2 = An @ An. 128 blocks x 128 threads.
// ---------------------------------------------------------------------------
__global__ void prep_a2(const float* __restrict__ An, float* __restrict__ A2) {
    const int i = blockIdx.x;
    const int j = threadIdx.x;
    float acc = 0.0f;
    for (int k = 0; k < N; ++k)
        acc += An[i * N + k] * An[k * N + j];
    A2[i * N + j] = acc;
}

// ---------------------------------------------------------------------------
// prep3: split lin_w and A2 into bf16 hi/lo, pre-arranged in MFMA fragment
// order so the main kernel loads them as coalesced dwordx4 per lane.
// Fragment k-pattern for 16x16x32: k = 32*kt + 4*(lane>>4) + (j&3) + 16*(j>>2).
// W (B-operand, 128x64): frag fr = kt*4+nt (16 frags), idx (fr*64+lane)*8+j.
// A2 (A-operand, 128x128): frag fr = kt*8+mt (32 frags), idx (fr*64+lane)*8+j.
// (Layout HW-verified: R2 passed with absmax = fp32 baseline.)
// ---------------------------------------------------------------------------
__global__ void prep_frag(const float* __restrict__ A2,
                          const float* __restrict__ lin_w,
                          u16* __restrict__ wfh, u16* __restrict__ wfl,
                          u16* __restrict__ afh, u16* __restrict__ afl) {
  int g = blockIdx.x * 256 + threadIdx.x;   // 0..3071
  if (g < 1024) {
    int fr = g >> 6, l = g & 63;
    int kt = fr >> 2, nt = fr & 3;
    int q = l >> 4, cc = l & 15;
#pragma unroll
    for (int j = 0; j < 8; ++j) {
      int k = 32 * kt + 4 * q + (j & 3) + 16 * (j >> 2);
      float v = lin_w[k * 64 + 16 * nt + cc];
      u32 u = __float_as_uint(v);
      wfh[(fr * 64 + l) * 8 + j] = (u16)(u >> 16);
      wfl[(fr * 64 + l) * 8 + j] = rne16(v - __uint_as_float(u & 0xffff0000u));
    }
  } else if (g < 3072) {
    int g2 = g - 1024;
    int fr = g2 >> 6, l = g2 & 63;        // fr = kt*8 + mt
    int kt = fr >> 3, mt = fr & 7;
    int q = l >> 4, rr = l & 15;
#pragma unroll
    for (int j = 0; j < 8; ++j) {
      int k = 32 * kt + 4 * q + (j & 3) + 16 * (j >> 2);
      float v = A2[(16 * mt + rr) * N + k];
      u32 u = __float_as_uint(v);
      afh[(fr * 64 + l) * 8 + j] = (u16)(u >> 16);
      afl[(fr * 64 + l) * 8 + j] = rne16(v - __uint_as_float(u & 0xffff0000u));
    }
  }
}

// ---------------------------------------------------------------------------
// Main fused kernel, one batch element per block, 4 waves.
// Wave w owns output rows 32w..32w+31 (m-tiles 2w, 2w+1) in both phases.
//   Phase 1: Y = X @ W   (X A-frags loaded DIRECTLY global->reg: no wave
//            shares X rows, so LDS staging/barriers were pure overhead.
//            Per-load coalescing: 4 q-lanes cover 64 contiguous B per row.)
//   Phase 2: H = A2 @ Y  (A2 frags from L2, Y^T hi/lo bf16 in LDS, str 140)
// Split-bf16 (hi+lo, 3 products; lo*lo dropped ~2^-18) on the matrix pipe,
// via the guide-verified short8 builtin (compiler handles MFMA hazards).
// LDS: 2 x 17.9 KB = 35 KB -> 4 blocks/CU (16 waves/CU for latency hiding).
// ---------------------------------------------------------------------------
__global__ __launch_bounds__(256, 4) void dgcnn_main(
    const float* __restrict__ x,
    const u16* __restrict__ wfh_, const u16* __restrict__ wfl_,
    const u16* __restrict__ afh_, const u16* __restrict__ afl_,
    const float* __restrict__ lin_b, const float* __restrict__ conv_w,
    const float* __restrict__ conv_b, const float* __restrict__ fc_w,
    const float* __restrict__ fc_b, float* __restrict__ out) {
  __shared__ __align__(16) u16 ythi[64 * YS];   // Y^T hi, 17920 B
  __shared__ __align__(16) u16 ytlo[64 * YS];   // Y^T lo, 17920 B

  const int t    = threadIdx.x;
  const int b    = blockIdx.x;
  const int w    = t >> 6;
  const int lane = t & 63;
  const int q    = lane >> 4;
  const int cl   = lane & 15;

  const float*  xb   = x + (size_t)b * (N * N);
  const bf16x8* wfh8 = (const bf16x8*)wfh_;
  const bf16x8* wfl8 = (const bf16x8*)wfl_;
  const bf16x8* afh8 = (const bf16x8*)afh_;
  const bf16x8* afl8 = (const bf16x8*)afl_;

  const f32x4 fzero = {0.f, 0.f, 0.f, 0.f};
  f32x4 acc[2][4];
#pragma unroll
  for (int m = 0; m < 2; ++m)
#pragma unroll
    for (int n = 0; n < 4; ++n) acc[m][n] = fzero;

  // ---------------- Phase 1: Y = X @ W, 4 k-chunks, no barriers ------------
#pragma unroll 1
  for (int c = 0; c < 4; ++c) {
    // W B-frags (hi/lo) from L2, coalesced 16B/lane, fr = c*4+nt < 16
    bf16x8 bh[4], bl[4];
#pragma unroll
    for (int nt = 0; nt < 4; ++nt) {
      bh[nt] = wfh8[(c * 4 + nt) * 64 + lane];
      bl[nt] = wfl8[(c * 4 + nt) * 64 + lane];
    }
    // X A-frags: direct global dwordx4 + in-register hi/lo split
    bf16x8 ah[2], al[2];
#pragma unroll
    for (int m = 0; m < 2; ++m) {
      const float* rp = xb + (32 * w + 16 * m + cl) * N + 32 * c + 4 * q;
      f32x4 x0 = *(const f32x4*)rp;          // k = 32c + 4q  .. +3
      f32x4 x1 = *(const f32x4*)(rp + 16);   // k = 32c + 16 + 4q .. +3
      cvt_frag(x0, x1, ah[m], al[m]);
    }
#pragma unroll
    for (int m = 0; m < 2; ++m)
#pragma unroll
      for (int nt = 0; nt < 4; ++nt) {
        acc[m][nt] = MFMA(ah[m], bh[nt], acc[m][nt]);
        acc[m][nt] = MFMA(ah[m], bl[nt], acc[m][nt]);
        acc[m][nt] = MFMA(al[m], bh[nt], acc[m][nt]);
      }
  }

  // Y -> Y^T hi/lo bf16 in LDS. D layout: row = 16*mt + 4q + r, col = 16nt+cl.
#pragma unroll
  for (int m = 0; m < 2; ++m) {
    int j0 = 32 * w + 16 * m + 4 * q;
#pragma unroll
    for (int nt = 0; nt < 4; ++nt) {
      int rbase = (16 * nt + cl) * YS + j0;
      f32x4 v = acc[m][nt];
      u32 hw0, lw0, hw1, lw1;
      cvt2(v.x, v.y, hw0, lw0);
      cvt2(v.z, v.w, hw1, lw1);
      i32x2 sh = {(int)hw0, (int)hw1};
      i32x2 sl = {(int)lw0, (int)lw1};
      *(i32x2*)&ythi[rbase] = sh;
      *(i32x2*)&ytlo[rbase] = sl;
      acc[m][nt] = fzero;
    }
  }
  __syncthreads();

  // ---------------- Phase 2: H = A2 @ Y (Y resident in LDS) ---------------
#pragma unroll 1
  for (int kt = 0; kt < 4; ++kt) {
    bf16x8 a2h[2], a2l[2];
#pragma unroll
    for (int m = 0; m < 2; ++m) {
      int fr = kt * 8 + 2 * w + m;
      a2h[m] = afh8[fr * 64 + lane];
      a2l[m] = afl8[fr * 64 + lane];
    }
#pragma unroll
    for (int nt = 0; nt < 4; ++nt) {
      int rbase = (16 * nt + cl) * YS + 32 * kt + 4 * q;
      i32x2 p0 = *(const i32x2*)&ythi[rbase];
      i32x2 p1 = *(const i32x2*)&ythi[rbase + 16];
      i32x2 r0 = *(const i32x2*)&ytlo[rbase];
      i32x2 r1 = *(const i32x2*)&ytlo[rbase + 16];
      bf16x8 yh = pack8((u32)p0.x, (u32)p0.y, (u32)p1.x, (u32)p1.y);
      bf16x8 yl = pack8((u32)r0.x, (u32)r0.y, (u32)r1.x, (u32)r1.y);
#pragma unroll
      for (int m = 0; m < 2; ++m) {
        acc[m][nt] = MFMA(a2h[m], yh, acc[m][nt]);
        acc[m][nt] = MFMA(a2h[m], yl, acc[m][nt]);
        acc[m][nt] = MFMA(a2l[m], yh, acc[m][nt]);
      }
    }
  }

  // Barrier: epilogue scratch aliases ythi — all phase-2 LDS reads must be
  // complete across the block before the first ps write.
  __syncthreads();

  // Epilogue: relu(H + lin_b) * conv_w, partial pool into LDS.
  float* ps   = (float*)ythi;          // 16 x 64 partials (4 KB)
  float* pool = (float*)ythi + 1024;   // 64 pooled
  float hb[4];
#pragma unroll
  for (int nt = 0; nt < 4; ++nt) hb[nt] = lin_b[16 * nt + cl];
  f32x4 cw0 = *(const f32x4*)(conv_w + 32 * w + 4 * q);
  f32x4 cw1 = *(const f32x4*)(conv_w + 32 * w + 16 + 4 * q);
#pragma unroll
  for (int nt = 0; nt < 4; ++nt) {
    f32x4 v0 = acc[0][nt], v1 = acc[1][nt];
    float s = 0.f;
    s += fmaxf(v0.x + hb[nt], 0.f) * cw0.x;
    s += fmaxf(v0.y + hb[nt], 0.f) * cw0.y;
    s += fmaxf(v0.z + hb[nt], 0.f) * cw0.z;
    s += fmaxf(v0.w + hb[nt], 0.f) * cw0.w;
    s += fmaxf(v1.x + hb[nt], 0.f) * cw1.x;
    s += fmaxf(v1.y + hb[nt], 0.f) * cw1.y;
    s += fmaxf(v1.z + hb[nt], 0.f) * cw1.z;
    s += fmaxf(v1.w + hb[nt], 0.f) * cw1.w;
    ps[(w * 4 + q) * 64 + 16 * nt + cl] = s;
  }
  __syncthreads();
  if (t < 64) {
    float s = conv_b[0];
#pragma unroll
    for (int i = 0; i < 16; ++i) s += ps[i * 64 + t];
    pool[t] = fmaxf(s, 0.f);
  }
  __syncthreads();
  if (t < NC) {
    float o = fc_b[t];
#pragma unroll
    for (int h = 0; h < 64; ++h) o += pool[h] * fc_w[h * NC + t];
    out[(size_t)b * NC + t] = o;
  }
}

// ---------------------------------------------------------------------------
extern "C" void kernel_launch(void* const* d_in, const int* in_sizes, int n_in,
                              void* d_out, int out_size, void* d_ws, size_t ws_size,
                              hipStream_t stream) {
    const float* x      = (const float*)d_in[0];
    const float* edge_w = (const float*)d_in[1];
    const float* lin_w  = (const float*)d_in[2];
    const float* lin_b  = (const float*)d_in[3];
    const float* conv_w = (const float*)d_in[4];
    const float* conv_b = (const float*)d_in[5];
    const float* fc_w   = (const float*)d_in[6];
    const float* fc_b   = (const float*)d_in[7];
    float* out = (float*)d_out;

    // workspace layout: A2(64K) An(64K) wfh(16K) wfl(16K) afh(32K) afl(32K)
    float* A2 = (float*)d_ws;
    float* An = A2 + N * N;
    u16* wfh = (u16*)(An + N * N);
    u16* wfl = wfh + 8192;
    u16* afh = wfl + 8192;
    u16* afl = afh + 16384;

    prep_anorm<<<1, 256, 0, stream>>>(edge_w, An);
    prep_a2<<<N, N, 0, stream>>>(An, A2);
    prep_frag<<<12, 256, 0, stream>>>(A2, lin_w, wfh, wfl, afh, afl);
    dgcnn_main<<<BB, 256, 0, stream>>>(x, wfh, wfl, afh, afl, lin_b, conv_w,
                                       conv_b, fc_w, fc_b, out);
}